// Round 1
// baseline (217.013 us; speedup 1.0000x reference)
//
#include <hip/hip_runtime.h>

#define N_SPIKES 16384
#define N_UNITS  256
#define N_NEIGHB 128
#define RANK     5
#define NC       64
#define NC_OBS   12
#define N_CAND   10
#define DD       60                 // RANK * NC_OBS
#define OUT_COLS 61
#define OUT_SIZE (N_UNITS * OUT_COLS)   // 15616
#define SPIKE_BLOCKS 256

// base constant: DD * log(2*pi), matching float32 cast of the python double
#define BASE_CONST ((float)(60.0 * 1.8378770664093453))

__device__ __forceinline__ float wave_reduce_sum(float v) {
#pragma unroll
    for (int off = 32; off > 0; off >>= 1) v += __shfl_xor(v, off, 64);
    return v;
}

// ---------------------------------------------------------------------------
// Kernel 1: per (neighborhood h, unit u) precompute
//   nu[d]  = mu[u, d/12, obs_ix[h, d%12]]
//   w      = Coo_inv[h] @ nu          (Coo_inv is symmetric by construction)
//   q2     = nu . w
// grid = 256 blocks (2 per h), block = 256 threads (4 waves, 32 units/wave)
// ---------------------------------------------------------------------------
__global__ __launch_bounds__(256) void precompute_kernel(
    const float* __restrict__ mu, const float* __restrict__ Coo_inv,
    const int* __restrict__ obs_ix,
    float* __restrict__ w_buf, float* __restrict__ q2_buf)
{
    __shared__ float sC[DD * DD];
    __shared__ int   sobs[NC_OBS];

    const int h   = blockIdx.x >> 1;
    const int u0  = (blockIdx.x & 1) * 128;
    const int tid = threadIdx.x;

    for (int i = tid; i < DD * DD; i += 256) sC[i] = Coo_inv[h * DD * DD + i];
    if (tid < NC_OBS) sobs[tid] = obs_ix[h * NC_OBS + tid];
    __syncthreads();

    const int lane = tid & 63;
    const int wave = tid >> 6;
    const int dl   = (lane < DD) ? lane : 0;
    const int r    = dl / NC_OBS;
    const int j    = dl % NC_OBS;
    const int col  = sobs[j];

    for (int ui = 0; ui < 32; ++ui) {
        const int u = u0 + wave * 32 + ui;
        const float nu = (lane < DD) ? mu[u * (RANK * NC) + r * NC + col] : 0.f;

        float w0 = 0.f, w1 = 0.f, w2 = 0.f, w3 = 0.f;
#pragma unroll
        for (int e = 0; e < DD; e += 4) {
            w0 += sC[(e + 0) * DD + dl] * __shfl(nu, e + 0, 64);
            w1 += sC[(e + 1) * DD + dl] * __shfl(nu, e + 1, 64);
            w2 += sC[(e + 2) * DD + dl] * __shfl(nu, e + 2, 64);
            w3 += sC[(e + 3) * DD + dl] * __shfl(nu, e + 3, 64);
        }
        const float w = (w0 + w1) + (w2 + w3);
        const float q2 = wave_reduce_sum((lane < DD) ? w * nu : 0.f);

        if (lane < DD) w_buf[(h * N_UNITS + u) * DD + lane] = w;
        if (lane == 0) q2_buf[h * N_UNITS + u] = q2;
    }
}

// ---------------------------------------------------------------------------
// Kernel 2: per-spike logliks + softmax + LDS-accumulated scatter
//   one wave per spike; 256 blocks x 4 waves x 16 spikes
//   mahal(c) = mnoise - 2*(w[h,u].xf) + q2[h,u]
//   block accumulator (256x61 f32) flushed to per-block partial buffer
// ---------------------------------------------------------------------------
__global__ __launch_bounds__(256) void spike_kernel(
    const float* __restrict__ features, const float* __restrict__ Coo_inv,
    const float* __restrict__ Coo_logdet, const float* __restrict__ log_prop,
    const float* __restrict__ noise_lp, const int* __restrict__ cands,
    const int* __restrict__ nid,
    const float* __restrict__ w_buf, const float* __restrict__ q2_buf,
    float* __restrict__ partials)
{
    __shared__ float acc[OUT_SIZE];

    const int tid = threadIdx.x;
    for (int i = tid; i < OUT_SIZE; i += 256) acc[i] = 0.f;
    __syncthreads();

    const int lane = tid & 63;
    const int wave = tid >> 6;
    const int dl   = (lane < DD) ? lane : 0;
    const float nlp = noise_lp[0];

    const int base_spike = blockIdx.x * 64 + wave * 16;

    for (int i = 0; i < 16; ++i) {
        const int n = base_spike + i;
        const int h = nid[n];
        const float xf = (lane < DD) ? features[n * DD + lane] : 0.f;

        // mnoise = xf^T Cinv xf  (use symmetry: read Cinv columns for coalescing)
        const float* __restrict__ Cb = Coo_inv + h * DD * DD;
        float y0 = 0.f, y1 = 0.f, y2 = 0.f, y3 = 0.f;
#pragma unroll
        for (int e = 0; e < DD; e += 4) {
            y0 += Cb[(e + 0) * DD + dl] * __shfl(xf, e + 0, 64);
            y1 += Cb[(e + 1) * DD + dl] * __shfl(xf, e + 1, 64);
            y2 += Cb[(e + 2) * DD + dl] * __shfl(xf, e + 2, 64);
            y3 += Cb[(e + 3) * DD + dl] * __shfl(xf, e + 3, 64);
        }
        const float y = (y0 + y1) + (y2 + y3);
        const float mnoise = wave_reduce_sum(xf * y);   // xf==0 masks lanes>=60
        const float basev = Coo_logdet[h] + BASE_CONST;

        int uc[N_CAND];
#pragma unroll
        for (int c = 0; c < N_CAND; ++c) uc[c] = cands[n * N_CAND + c];

        float wv[N_CAND];
#pragma unroll
        for (int c = 0; c < N_CAND; ++c)
            wv[c] = w_buf[(h * N_UNITS + uc[c]) * DD + dl];

        float ll[N_CAND];
#pragma unroll
        for (int c = 0; c < N_CAND; ++c) {
            const float dot = wave_reduce_sum(wv[c] * xf);
            const float q2  = q2_buf[h * N_UNITS + uc[c]];
            ll[c] = log_prop[uc[c]] - 0.5f * (basev + mnoise - 2.f * dot + q2);
        }
        const float lln = nlp - 0.5f * (basev + mnoise);

        float m = lln;
#pragma unroll
        for (int c = 0; c < N_CAND; ++c) m = fmaxf(m, ll[c]);
        float s = __expf(lln - m);
        float qv[N_CAND];
#pragma unroll
        for (int c = 0; c < N_CAND; ++c) { qv[c] = __expf(ll[c] - m); s += qv[c]; }
        const float inv = 1.f / s;

#pragma unroll
        for (int c = 0; c < N_CAND; ++c) {
            const float q = qv[c] * inv;
            const int u = uc[c];
            if (lane <= DD) {   // lanes 0..59: xsum, lane 60: count
                const int addr  = (lane < DD) ? (u * OUT_COLS + 1 + lane)
                                              : (u * OUT_COLS);
                const float val = (lane < DD) ? q * xf : q;
                atomicAdd(&acc[addr], val);
            }
        }
    }

    __syncthreads();
    float* __restrict__ pb = partials + (size_t)blockIdx.x * OUT_SIZE;
    for (int i = tid; i < OUT_SIZE; i += 256) pb[i] = acc[i];
}

// ---------------------------------------------------------------------------
// Kernel 3: reduce 256 partial buffers -> d_out
// ---------------------------------------------------------------------------
__global__ __launch_bounds__(256) void reduce_kernel(
    const float* __restrict__ partials, float* __restrict__ out)
{
    const int i = blockIdx.x * 256 + threadIdx.x;
    if (i < OUT_SIZE) {
        float s = 0.f;
        for (int b = 0; b < SPIKE_BLOCKS; ++b)
            s += partials[(size_t)b * OUT_SIZE + i];
        out[i] = s;
    }
}

extern "C" void kernel_launch(void* const* d_in, const int* in_sizes, int n_in,
                              void* d_out, int out_size, void* d_ws, size_t ws_size,
                              hipStream_t stream) {
    const float* features    = (const float*)d_in[0];
    const float* mu          = (const float*)d_in[1];
    const float* Coo_inv     = (const float*)d_in[2];
    const float* Coo_logdet  = (const float*)d_in[3];
    const float* log_prop    = (const float*)d_in[4];
    const float* noise_lp    = (const float*)d_in[5];
    const int*   cands       = (const int*)d_in[6];
    const int*   nid         = (const int*)d_in[7];
    const int*   obs_ix      = (const int*)d_in[8];
    float* out = (float*)d_out;

    char* ws = (char*)d_ws;
    float* w_buf    = (float*)ws;                                   // 128*256*60*4 = 7,864,320 B
    float* q2_buf   = (float*)(ws + 7864320);                       // 128*256*4    =   131,072 B
    float* partials = (float*)(ws + 7864320 + 131072);              // 256*15616*4  = 15,990,784 B

    precompute_kernel<<<256, 256, 0, stream>>>(mu, Coo_inv, obs_ix, w_buf, q2_buf);
    spike_kernel<<<SPIKE_BLOCKS, 256, 0, stream>>>(features, Coo_inv, Coo_logdet,
                                                   log_prop, noise_lp, cands, nid,
                                                   w_buf, q2_buf, partials);
    reduce_kernel<<<(OUT_SIZE + 255) / 256, 256, 0, stream>>>(partials, out);
}

// Round 2
// 182.443 us; speedup vs baseline: 1.1895x; 1.1895x over previous
//
#include <hip/hip_runtime.h>

#define N_SPIKES 16384
#define N_UNITS  256
#define N_NEIGHB 128
#define RANK     5
#define NC       64
#define NC_OBS   12
#define N_CAND   10
#define DD       60                 // RANK * NC_OBS
#define OUT_COLS 61
#define OUT_SIZE (N_UNITS * OUT_COLS)   // 15616
#define SPIKE_BLOCKS 256

__device__ __forceinline__ float wave_reduce_sum(float v) {
#pragma unroll
    for (int off = 32; off > 0; off >>= 1) v += __shfl_xor(v, off, 64);
    return v;
}

// ---------------------------------------------------------------------------
// Kernel 1: per (h, u) precompute
//   nu[d] = mu[u, d/12, obs_ix[h, d%12]]
//   w     = Coo_inv[h] @ nu      (Coo_inv symmetric)
//   b     = log_prop[u] - 0.5 * nu.w
// grid = 1024 blocks (8 per h, 32 units each), block = 256 (4 waves x 8 units)
// ---------------------------------------------------------------------------
__global__ __launch_bounds__(256) void precompute_kernel(
    const float* __restrict__ mu, const float* __restrict__ Coo_inv,
    const int* __restrict__ obs_ix, const float* __restrict__ log_prop,
    float* __restrict__ w_buf, float* __restrict__ b_buf)
{
    __shared__ float sC[DD * DD];
    __shared__ int   sobs[NC_OBS];

    const int h   = blockIdx.x >> 3;
    const int u0  = (blockIdx.x & 7) * 32;
    const int tid = threadIdx.x;

    for (int i = tid; i < DD * DD; i += 256) sC[i] = Coo_inv[h * DD * DD + i];
    if (tid < NC_OBS) sobs[tid] = obs_ix[h * NC_OBS + tid];
    __syncthreads();

    const int lane = tid & 63;
    const int wave = tid >> 6;
    const int dl   = (lane < DD) ? lane : 0;
    const int r    = dl / NC_OBS;
    const int j    = dl % NC_OBS;
    const int col  = sobs[j];

    for (int ui = 0; ui < 8; ++ui) {
        const int u = u0 + wave * 8 + ui;
        const float nu = (lane < DD) ? mu[u * (RANK * NC) + r * NC + col] : 0.f;

        float w0 = 0.f, w1 = 0.f, w2 = 0.f, w3 = 0.f;
#pragma unroll
        for (int e = 0; e < DD; e += 4) {
            w0 += sC[(e + 0) * DD + dl] * __shfl(nu, e + 0, 64);
            w1 += sC[(e + 1) * DD + dl] * __shfl(nu, e + 1, 64);
            w2 += sC[(e + 2) * DD + dl] * __shfl(nu, e + 2, 64);
            w3 += sC[(e + 3) * DD + dl] * __shfl(nu, e + 3, 64);
        }
        const float w = (w0 + w1) + (w2 + w3);
        const float q2 = wave_reduce_sum((lane < DD) ? w * nu : 0.f);

        if (lane < DD) w_buf[(h * N_UNITS + u) * DD + lane] = w;
        if (lane == 0) b_buf[h * N_UNITS + u] = log_prop[u] - 0.5f * q2;
    }
}

// ---------------------------------------------------------------------------
// Kernel 2: per-spike softmax + scatter. The common term -0.5*(base+mnoise)
// cancels in softmax, so NO per-spike Cinv matvec is needed:
//   ll_c = b[h,u_c] + w[h,u_c].xf     vs noise logit = noise_log_prop
// one wave per spike batch: 256 blocks x 8 waves x 8 spikes
// ---------------------------------------------------------------------------
__global__ __launch_bounds__(512) void spike_kernel(
    const float* __restrict__ features, const float* __restrict__ noise_lp,
    const int* __restrict__ cands, const int* __restrict__ nid,
    const float* __restrict__ w_buf, const float* __restrict__ b_buf,
    float* __restrict__ partials)
{
    __shared__ float acc[OUT_SIZE];

    const int tid = threadIdx.x;
    for (int i = tid; i < OUT_SIZE; i += 512) acc[i] = 0.f;
    __syncthreads();

    const int lane = tid & 63;
    const int wave = tid >> 6;
    const int dl   = (lane < DD) ? lane : 0;
    const float nlp = noise_lp[0];

    const int base_spike = blockIdx.x * 64 + wave * 8;

    for (int i = 0; i < 8; ++i) {
        const int n = base_spike + i;
        const int h = nid[n];
        const float xf = (lane < DD) ? features[n * DD + lane] : 0.f;

        int uc[N_CAND];
#pragma unroll
        for (int c = 0; c < N_CAND; ++c) uc[c] = cands[n * N_CAND + c];

        float wv[N_CAND], bb[N_CAND];
#pragma unroll
        for (int c = 0; c < N_CAND; ++c) {
            const int p = h * N_UNITS + uc[c];
            wv[c] = w_buf[p * DD + dl];
            bb[c] = b_buf[p];
        }

        float ll[N_CAND];
#pragma unroll
        for (int c = 0; c < N_CAND; ++c)
            ll[c] = bb[c] + wave_reduce_sum(wv[c] * xf);

        float m = nlp;
#pragma unroll
        for (int c = 0; c < N_CAND; ++c) m = fmaxf(m, ll[c]);
        float s = __expf(nlp - m);
        float qv[N_CAND];
#pragma unroll
        for (int c = 0; c < N_CAND; ++c) { qv[c] = __expf(ll[c] - m); s += qv[c]; }
        const float inv = 1.f / s;

#pragma unroll
        for (int c = 0; c < N_CAND; ++c) {
            const float q = qv[c] * inv;
            const int u = uc[c];
            if (lane <= DD) {   // lanes 0..59: xsum, lane 60: count
                const int addr  = (lane < DD) ? (u * OUT_COLS + 1 + lane)
                                              : (u * OUT_COLS);
                const float val = (lane < DD) ? q * xf : q;
                atomicAdd(&acc[addr], val);
            }
        }
    }

    __syncthreads();
    float* __restrict__ pb = partials + (size_t)blockIdx.x * OUT_SIZE;
    for (int i = tid; i < OUT_SIZE; i += 512) pb[i] = acc[i];
}

// ---------------------------------------------------------------------------
// Kernel 3: reduce 256 partial buffers -> d_out
// grid = 244 blocks x 256 thr; each block owns 64 consecutive outputs,
// 4 thread-groups split the 256 partials, LDS tree at the end.
// ---------------------------------------------------------------------------
__global__ __launch_bounds__(256) void reduce_kernel(
    const float* __restrict__ partials, float* __restrict__ out)
{
    __shared__ float red[256];
    const int tid = threadIdx.x;
    const int col = blockIdx.x * 64 + (tid & 63);
    const int grp = tid >> 6;

    float s = 0.f;
#pragma unroll 8
    for (int b = grp; b < SPIKE_BLOCKS; b += 4)
        s += partials[(size_t)b * OUT_SIZE + col];

    red[tid] = s;
    __syncthreads();
    if (tid < 64)
        out[col] = (red[tid] + red[tid + 64]) + (red[tid + 128] + red[tid + 192]);
}

extern "C" void kernel_launch(void* const* d_in, const int* in_sizes, int n_in,
                              void* d_out, int out_size, void* d_ws, size_t ws_size,
                              hipStream_t stream) {
    const float* features    = (const float*)d_in[0];
    const float* mu          = (const float*)d_in[1];
    const float* Coo_inv     = (const float*)d_in[2];
    // d_in[3] = Coo_logdet : unused (cancels in softmax)
    const float* log_prop    = (const float*)d_in[4];
    const float* noise_lp    = (const float*)d_in[5];
    const int*   cands       = (const int*)d_in[6];
    const int*   nid         = (const int*)d_in[7];
    const int*   obs_ix      = (const int*)d_in[8];
    float* out = (float*)d_out;

    char* ws = (char*)d_ws;
    float* w_buf    = (float*)ws;                                   // 128*256*60*4 = 7,864,320 B
    float* b_buf    = (float*)(ws + 7864320);                       // 128*256*4    =   131,072 B
    float* partials = (float*)(ws + 7864320 + 131072);              // 256*15616*4  = 15,990,784 B

    precompute_kernel<<<1024, 256, 0, stream>>>(mu, Coo_inv, obs_ix, log_prop,
                                                w_buf, b_buf);
    spike_kernel<<<SPIKE_BLOCKS, 512, 0, stream>>>(features, noise_lp, cands, nid,
                                                   w_buf, b_buf, partials);
    reduce_kernel<<<244, 256, 0, stream>>>(partials, out);
}

// Round 3
// 170.629 us; speedup vs baseline: 1.2718x; 1.0692x over previous
//
#include <hip/hip_runtime.h>

#define N_SPIKES 16384
#define N_UNITS  256
#define N_NEIGHB 128
#define RANK     5
#define NC       64
#define NC_OBS   12
#define N_CAND   10
#define DD       60                 // RANK * NC_OBS
#define DD4      15                 // DD / 4
#define OUT_COLS 61
#define OUT_SIZE (N_UNITS * OUT_COLS)   // 15616
#define SPIKE_BLOCKS 256

// ---------------------------------------------------------------------------
// Kernel A: gather nu[h,u,:] = mu[u, d/12, obs_ix[h, d%12]] into nu_buf.
// lanes = dims (coalesced writes, ~20-line gather reads). 1024 blocks,
// 32 units each (4 waves x 8).
// ---------------------------------------------------------------------------
__global__ __launch_bounds__(256, 2) void nu_gather_kernel(
    const float* __restrict__ mu, const int* __restrict__ obs_ix,
    float* __restrict__ nu_buf)
{
    __shared__ int sobs[NC_OBS];
    const int h   = blockIdx.x >> 3;
    const int u0  = (blockIdx.x & 7) * 32;
    const int tid = threadIdx.x;
    if (tid < NC_OBS) sobs[tid] = obs_ix[h * NC_OBS + tid];
    __syncthreads();

    const int lane = tid & 63;
    const int wave = tid >> 6;
    const int dl   = (lane < DD) ? lane : 0;
    const int r    = dl / NC_OBS;
    const int j    = dl - r * NC_OBS;
    const int col  = sobs[j];
    const int ub   = u0 + wave * 8;

#pragma unroll
    for (int ui = 0; ui < 8; ++ui) {
        const int u = ub + ui;
        const float v = mu[u * (RANK * NC) + r * NC + col];
        if (lane < DD) nu_buf[(h * N_UNITS + u) * DD + lane] = v;
    }
}

// ---------------------------------------------------------------------------
// Kernel B: w[h,u,:] = Coo_inv[h] @ nu[h,u,:],  b = log_prop[u] - 0.5*nu.w
// Lane-owns-unit: zero cross-lane ops. C rows via wave-uniform loads
// (s_load; C is symmetric so row e == column e). nu staged in a padded
// per-wave LDS tile for the dynamically-indexed e-loop; q2 in-lane from
// the register copy. 256 blocks x 128 thr (2 waves x 64 units).
// ---------------------------------------------------------------------------
__global__ __launch_bounds__(128, 1) void matvec_kernel(
    const float* __restrict__ Coo_inv, const float* __restrict__ log_prop,
    const float* __restrict__ nu_buf,
    float* __restrict__ w_buf, float* __restrict__ b_buf)
{
    __shared__ float tile[2][64 * 61];   // per-wave, pad 61: conflict-free

    const int h    = blockIdx.x >> 1;
    const int lane = threadIdx.x & 63;
    const int wave = threadIdx.x >> 6;
    const int u    = (blockIdx.x & 1) * 128 + wave * 64 + lane;
    const int p    = h * N_UNITS + u;
    float* tl = &tile[wave][lane * 61];

    // stage nu: float4 global loads (kept in regs for q2) + LDS for e-loop
    float4 nu4[DD4];
#pragma unroll
    for (int k = 0; k < DD4; ++k) {
        nu4[k] = ((const float4*)nu_buf)[p * DD4 + k];
        tl[4*k+0] = nu4[k].x; tl[4*k+1] = nu4[k].y;
        tl[4*k+2] = nu4[k].z; tl[4*k+3] = nu4[k].w;
    }
    // wave-private tile: no barrier needed (compiler inserts lgkmcnt waits)

    float wreg[DD];
#pragma unroll
    for (int d = 0; d < DD; ++d) wreg[d] = 0.f;

    const float* __restrict__ C = Coo_inv + h * DD * DD;
    for (int e = 0; e < DD; ++e) {
        const float nu_e = tl[e];                      // ds_read, stride-61
        const float* __restrict__ Crow = C + e * DD;   // uniform -> s_load
#pragma unroll
        for (int d = 0; d < DD; ++d)
            wreg[d] = fmaf(Crow[d], nu_e, wreg[d]);
    }

    float q2 = 0.f;
#pragma unroll
    for (int k = 0; k < DD4; ++k)
        q2 += wreg[4*k+0]*nu4[k].x + wreg[4*k+1]*nu4[k].y
            + wreg[4*k+2]*nu4[k].z + wreg[4*k+3]*nu4[k].w;

#pragma unroll
    for (int k = 0; k < DD4; ++k) {
        float4 o;
        o.x = wreg[4*k+0]; o.y = wreg[4*k+1];
        o.z = wreg[4*k+2]; o.w = wreg[4*k+3];
        ((float4*)w_buf)[p * DD4 + k] = o;
    }
    b_buf[p] = log_prop[u] - 0.5f * q2;
}

// ---------------------------------------------------------------------------
// Kernel 2: per-spike softmax + scatter. 16-lane float4 groups: 4 spikes
// per wave simultaneously; each dot = 4 FMA + 4 shfl_xor (shared across
// groups per instruction). Softmax fully in-lane. 256 blocks x 512 thr,
// 8 spikes per wave (2 iters x 4).
// ---------------------------------------------------------------------------
__global__ __launch_bounds__(512, 2) void spike_kernel(
    const float* __restrict__ features, const float* __restrict__ noise_lp,
    const int* __restrict__ cands, const int* __restrict__ nid,
    const float* __restrict__ w_buf, const float* __restrict__ b_buf,
    float* __restrict__ partials)
{
    __shared__ float acc[OUT_SIZE];
    const int tid = threadIdx.x;
    for (int i = tid; i < OUT_SIZE; i += 512) acc[i] = 0.f;
    __syncthreads();

    const int lane = tid & 63;
    const int wave = tid >> 6;
    const int l = lane & 15;          // dim-chunk within group
    const int s = lane >> 4;          // spike slot within wave
    const bool dimlane = (l < DD4);   // lanes 0..14 hold float4 dims
    const float nlp = noise_lp[0];
    const float4* __restrict__ f4 = (const float4*)features;
    const float4* __restrict__ w4 = (const float4*)w_buf;
    const float4 z4 = {0.f, 0.f, 0.f, 0.f};

    const int base = blockIdx.x * 64 + wave * 8;

#pragma unroll
    for (int it = 0; it < 2; ++it) {
        const int n = base + it * 4 + s;
        const int h = nid[n];
        const float4 xf = dimlane ? f4[n * DD4 + l] : z4;

        int uc[N_CAND];
#pragma unroll
        for (int c = 0; c < N_CAND; ++c) uc[c] = cands[n * N_CAND + c];

        float4 wv[N_CAND]; float bb[N_CAND];
#pragma unroll
        for (int c = 0; c < N_CAND; ++c) {
            const int p = h * N_UNITS + uc[c];
            wv[c] = dimlane ? w4[p * DD4 + l] : z4;
            bb[c] = b_buf[p];
        }

        float ll[N_CAND];
#pragma unroll
        for (int c = 0; c < N_CAND; ++c) {
            float t = wv[c].x*xf.x + wv[c].y*xf.y + wv[c].z*xf.z + wv[c].w*xf.w;
            t += __shfl_xor(t, 8, 64);
            t += __shfl_xor(t, 4, 64);
            t += __shfl_xor(t, 2, 64);
            t += __shfl_xor(t, 1, 64);
            ll[c] = bb[c] + t;
        }

        float m = nlp;
#pragma unroll
        for (int c = 0; c < N_CAND; ++c) m = fmaxf(m, ll[c]);
        float ssum = __expf(nlp - m);
        float qv[N_CAND];
#pragma unroll
        for (int c = 0; c < N_CAND; ++c) { qv[c] = __expf(ll[c] - m); ssum += qv[c]; }
        const float inv = 1.f / ssum;

#pragma unroll
        for (int c = 0; c < N_CAND; ++c) {
            const float q = qv[c] * inv;
            const int ub = uc[c] * OUT_COLS;
            if (dimlane) {
                const int a = ub + 1 + l * 4;
                atomicAdd(&acc[a + 0], q * xf.x);
                atomicAdd(&acc[a + 1], q * xf.y);
                atomicAdd(&acc[a + 2], q * xf.z);
                atomicAdd(&acc[a + 3], q * xf.w);
            } else if (l == DD4) {    // one lane per group: the count column
                atomicAdd(&acc[ub], q);
            }
        }
    }

    __syncthreads();
    float* __restrict__ pb = partials + (size_t)blockIdx.x * OUT_SIZE;
    for (int i = tid; i < OUT_SIZE; i += 512) pb[i] = acc[i];
}

// ---------------------------------------------------------------------------
// Kernel 3: reduce 256 partial buffers -> d_out
// ---------------------------------------------------------------------------
__global__ __launch_bounds__(256) void reduce_kernel(
    const float* __restrict__ partials, float* __restrict__ out)
{
    __shared__ float red[256];
    const int tid = threadIdx.x;
    const int col = blockIdx.x * 64 + (tid & 63);
    const int grp = tid >> 6;

    float s = 0.f;
#pragma unroll 8
    for (int b = grp; b < SPIKE_BLOCKS; b += 4)
        s += partials[(size_t)b * OUT_SIZE + col];

    red[tid] = s;
    __syncthreads();
    if (tid < 64)
        out[col] = (red[tid] + red[tid + 64]) + (red[tid + 128] + red[tid + 192]);
}

extern "C" void kernel_launch(void* const* d_in, const int* in_sizes, int n_in,
                              void* d_out, int out_size, void* d_ws, size_t ws_size,
                              hipStream_t stream) {
    const float* features    = (const float*)d_in[0];
    const float* mu          = (const float*)d_in[1];
    const float* Coo_inv     = (const float*)d_in[2];
    // d_in[3] = Coo_logdet : unused (cancels in softmax)
    const float* log_prop    = (const float*)d_in[4];
    const float* noise_lp    = (const float*)d_in[5];
    const int*   cands       = (const int*)d_in[6];
    const int*   nid         = (const int*)d_in[7];
    const int*   obs_ix      = (const int*)d_in[8];
    float* out = (float*)d_out;

    char* ws = (char*)d_ws;
    // nu_buf (7.86 MB) aliases the partials region (16 MB): nu is fully
    // consumed by matvec_kernel before spike_kernel overwrites partials.
    float* partials = (float*)ws;                                   // 256*15616*4 = 15,990,784 B
    float* nu_buf   = (float*)ws;                                   // 128*256*60*4 = 7,864,320 B (alias)
    float* w_buf    = (float*)(ws + 15990784);                      // 128*256*60*4 = 7,864,320 B
    float* b_buf    = (float*)(ws + 15990784 + 7864320);            // 128*256*4    =   131,072 B

    nu_gather_kernel<<<1024, 256, 0, stream>>>(mu, obs_ix, nu_buf);
    matvec_kernel<<<256, 128, 0, stream>>>(Coo_inv, log_prop, nu_buf, w_buf, b_buf);
    spike_kernel<<<SPIKE_BLOCKS, 512, 0, stream>>>(features, noise_lp, cands, nid,
                                                   w_buf, b_buf, partials);
    reduce_kernel<<<244, 256, 0, stream>>>(partials, out);
}

// Round 4
// 168.915 us; speedup vs baseline: 1.2847x; 1.0101x over previous
//
#include <hip/hip_runtime.h>

#define N_SPIKES 16384
#define N_UNITS  256
#define N_NEIGHB 128
#define RANK     5
#define NC       64
#define NC_OBS   12
#define N_CAND   10
#define DD       60                 // RANK * NC_OBS
#define DD4      15                 // DD / 4
#define OUT_COLS 61
#define OUT_SIZE (N_UNITS * OUT_COLS)   // 15616

// ---------------------------------------------------------------------------
// Kernel P: fused nu-gather + matvec.  Lane owns unit u.
//   nu[d] = mu[u, d/12, obs_ix[h, d%12]]   (gathered straight into LDS tile)
//   w     = Coo_inv[h] @ nu                (C rows wave-uniform -> scalarized)
//   b     = log_prop[u] - 0.5 * nu.w
// grid = 256 blocks (2 per h, 128 units), block = 128 (2 waves x 64 lanes)
// ---------------------------------------------------------------------------
__global__ __launch_bounds__(128) void precompute_kernel(
    const float* __restrict__ mu, const float* __restrict__ Coo_inv,
    const int* __restrict__ obs_ix, const float* __restrict__ log_prop,
    float* __restrict__ w_buf, float* __restrict__ b_buf)
{
    __shared__ float tile[128 * 61];   // per-lane nu, stride 61 (odd: conflict-free)

    const int h    = blockIdx.x >> 1;
    const int tid  = threadIdx.x;
    const int lane = tid & 63;
    const int wave = tid >> 6;
    const int u    = (blockIdx.x & 1) * 128 + wave * 64 + lane;
    const int p    = h * N_UNITS + u;

    int so[NC_OBS];
#pragma unroll
    for (int j = 0; j < NC_OBS; ++j) so[j] = obs_ix[h * NC_OBS + j];

    // gather nu directly into the LDS tile (r-major: 12 loads share L1 lines)
    const float* __restrict__ mub = mu + u * (RANK * NC);
    float* tl = &tile[tid * 61];
#pragma unroll
    for (int d = 0; d < DD; ++d) {
        const int r = d / NC_OBS;
        const int j = d - r * NC_OBS;
        tl[d] = mub[r * NC + so[j]];
    }

    float wreg[DD];
#pragma unroll
    for (int d = 0; d < DD; ++d) wreg[d] = 0.f;

    const float* __restrict__ C = Coo_inv + h * DD * DD;
    for (int e = 0; e < DD; ++e) {
        const float nu_e = tl[e];                      // ds_read, per-lane
        const float* __restrict__ Crow = C + e * DD;   // wave-uniform
#pragma unroll
        for (int d = 0; d < DD; ++d)
            wreg[d] = fmaf(Crow[d], nu_e, wreg[d]);
    }

    float q2 = 0.f;
#pragma unroll
    for (int d = 0; d < DD; ++d) q2 += wreg[d] * tl[d];   // static ds_reads

#pragma unroll
    for (int k = 0; k < DD4; ++k) {
        float4 o;
        o.x = wreg[4*k+0]; o.y = wreg[4*k+1];
        o.z = wreg[4*k+2]; o.w = wreg[4*k+3];
        ((float4*)w_buf)[p * DD4 + k] = o;
    }
    b_buf[p] = log_prop[u] - 0.5f * q2;
}

// ---------------------------------------------------------------------------
// Kernel S: per-spike softmax + scatter.  16-lane float4 groups, exactly
// 4 spikes per wave (no outer loop).  512 blocks x 512 thr = 16384 spikes.
// LDS acc 62.5 KB -> 2 blocks/CU = 16 waves/CU resident.  Flush via global
// fire-and-forget atomics into pre-zeroed d_out (no partials/reduce pass).
// ---------------------------------------------------------------------------
__global__ __launch_bounds__(512, 4) void spike_kernel(
    const float* __restrict__ features, const float* __restrict__ noise_lp,
    const int* __restrict__ cands, const int* __restrict__ nid,
    const float* __restrict__ w_buf, const float* __restrict__ b_buf,
    float* __restrict__ out)
{
    __shared__ float acc[OUT_SIZE];
    const int tid = threadIdx.x;
    for (int i = tid; i < OUT_SIZE; i += 512) acc[i] = 0.f;

    const int lane = tid & 63;
    const int wave = tid >> 6;
    const int l = lane & 15;          // dim-chunk within group
    const int s = lane >> 4;          // spike slot within wave
    const bool dimlane = (l < DD4);   // lanes 0..14 hold float4 dims
    const int n = blockIdx.x * 32 + wave * 4 + s;

    // issue all independent loads up front
    const float4* __restrict__ f4 = (const float4*)features;
    const float4* __restrict__ w4 = (const float4*)w_buf;
    const float4 z4 = {0.f, 0.f, 0.f, 0.f};
    const float4 xf = dimlane ? f4[n * DD4 + l] : z4;
    const int h = nid[n];
    const float nlp = noise_lp[0];
    int uc[N_CAND];
#pragma unroll
    for (int c = 0; c < N_CAND; ++c) uc[c] = cands[n * N_CAND + c];

    float4 wv[N_CAND]; float bb[N_CAND];
#pragma unroll
    for (int c = 0; c < N_CAND; ++c) {
        const int p = h * N_UNITS + uc[c];
        wv[c] = dimlane ? w4[p * DD4 + l] : z4;
        bb[c] = b_buf[p];
    }

    float ll[N_CAND];
#pragma unroll
    for (int c = 0; c < N_CAND; ++c) {
        float t = wv[c].x*xf.x + wv[c].y*xf.y + wv[c].z*xf.z + wv[c].w*xf.w;
        t += __shfl_xor(t, 8, 64);
        t += __shfl_xor(t, 4, 64);
        t += __shfl_xor(t, 2, 64);
        t += __shfl_xor(t, 1, 64);
        ll[c] = bb[c] + t;
    }

    float m = nlp;
#pragma unroll
    for (int c = 0; c < N_CAND; ++c) m = fmaxf(m, ll[c]);
    float ssum = __expf(nlp - m);
    float qv[N_CAND];
#pragma unroll
    for (int c = 0; c < N_CAND; ++c) { qv[c] = __expf(ll[c] - m); ssum += qv[c]; }
    const float inv = 1.f / ssum;

    __syncthreads();   // acc zero-init complete

#pragma unroll
    for (int c = 0; c < N_CAND; ++c) {
        const float q = qv[c] * inv;
        const int ub = uc[c] * OUT_COLS;
        if (dimlane) {
            const int a = ub + 1 + l * 4;
            atomicAdd(&acc[a + 0], q * xf.x);
            atomicAdd(&acc[a + 1], q * xf.y);
            atomicAdd(&acc[a + 2], q * xf.z);
            atomicAdd(&acc[a + 3], q * xf.w);
        } else if (l == DD4) {        // one lane per group: count column
            atomicAdd(&acc[ub], q);
        }
    }

    __syncthreads();
    // flush to pre-zeroed global out; skip zeros (saves ~30% of atomics)
    for (int i = tid; i < OUT_SIZE; i += 512) {
        const float v = acc[i];
        if (v != 0.f) atomicAdd(&out[i], v);
    }
}

extern "C" void kernel_launch(void* const* d_in, const int* in_sizes, int n_in,
                              void* d_out, int out_size, void* d_ws, size_t ws_size,
                              hipStream_t stream) {
    const float* features    = (const float*)d_in[0];
    const float* mu          = (const float*)d_in[1];
    const float* Coo_inv     = (const float*)d_in[2];
    // d_in[3] = Coo_logdet : unused (cancels in softmax)
    const float* log_prop    = (const float*)d_in[4];
    const float* noise_lp    = (const float*)d_in[5];
    const int*   cands       = (const int*)d_in[6];
    const int*   nid         = (const int*)d_in[7];
    const int*   obs_ix      = (const int*)d_in[8];
    float* out = (float*)d_out;

    char* ws = (char*)d_ws;
    float* w_buf = (float*)ws;                    // 128*256*60*4 = 7,864,320 B
    float* b_buf = (float*)(ws + 7864320);        // 128*256*4    =   131,072 B

    hipMemsetAsync(d_out, 0, (size_t)out_size * sizeof(float), stream);
    precompute_kernel<<<256, 128, 0, stream>>>(mu, Coo_inv, obs_ix, log_prop,
                                               w_buf, b_buf);
    spike_kernel<<<512, 512, 0, stream>>>(features, noise_lp, cands, nid,
                                          w_buf, b_buf, out);
}